// Round 1
// baseline (462.580 us; speedup 1.0000x reference)
//
#include <hip/hip_runtime.h>
#include <math.h>

constexpr int V = 32000, H = 1024, E = 1024, B = 64, S = 128;
constexpr int KX = 2048;                      // xcat = [emb | context]

// d_out offsets (floats), return order: logprobs, h1, c1, attn_weights
constexpr long long OUT_H1   = (long long)B * V;      // 2048000
constexpr long long OUT_C1   = OUT_H1 + (long long)B * H;
constexpr long long OUT_ATTN = OUT_C1 + (long long)B * H;

// ws offsets (floats)
constexpr long long WS_SCORES = 0;                                  // B*S
constexpr long long WS_XCAT   = WS_SCORES + (long long)B * S;       // B*2048
constexpr long long WS_PART   = WS_XCAT + (long long)B * KX;        // 6*B*4096
constexpr long long WS_CTXP   = WS_PART + 6LL * B * 4096;           // 4*B*H
constexpr long long WS_PM     = WS_CTXP + 4LL * B * H;              // 512
constexpr long long WS_PL     = WS_PM + 512;                        // 512
constexpr long long WS_LC     = WS_PL + 512;                        // 64

// ---------------- K1: e_part[b,s] = dot(enc[b,s,:], attn_w[H:]) -------------
__global__ __launch_bounds__(256) void k_scores(
    const float* __restrict__ enc, const float* __restrict__ attn_w,
    float* __restrict__ scores) {
  int w = (blockIdx.x * 256 + threadIdx.x) >> 6;   // (b*S+s) in [0, 8192)
  int lane = threadIdx.x & 63;
  const float4* e4 = (const float4*)(enc + (long long)w * H);
  const float4* w4 = (const float4*)(attn_w + H);
  float acc = 0.f;
#pragma unroll
  for (int i = 0; i < 4; ++i) {
    float4 a = e4[lane + 64 * i];
    float4 b = w4[lane + 64 * i];
    acc += a.x * b.x + a.y * b.y + a.z * b.z + a.w * b.w;
  }
#pragma unroll
  for (int m = 32; m; m >>= 1) acc += __shfl_xor(acc, m, 64);
  if (lane == 0) scores[w] = acc;
}

// ---------------- K2: h_part + softmax over S, write attn weights -----------
__global__ __launch_bounds__(128) void k_softmax(
    const float* __restrict__ scores, const float* __restrict__ h0,
    const float* __restrict__ attn_w, const float* __restrict__ attn_b,
    float* __restrict__ attn_out) {
  __shared__ float red[128];
  int b = blockIdx.x, t = threadIdx.x;
  float p = 0.f;
#pragma unroll
  for (int j = 0; j < 8; ++j) {
    int k = t + 128 * j;
    p += h0[b * H + k] * attn_w[k];
  }
  red[t] = p; __syncthreads();
  for (int off = 64; off > 0; off >>= 1) {
    if (t < off) red[t] += red[t + off];
    __syncthreads();
  }
  float hp = red[0]; __syncthreads();
  float sc = scores[b * S + t] + hp + attn_b[0];
  red[t] = sc; __syncthreads();
  for (int off = 64; off > 0; off >>= 1) {
    if (t < off) red[t] = fmaxf(red[t], red[t + off]);
    __syncthreads();
  }
  float m = red[0]; __syncthreads();
  float e = expf(sc - m);
  red[t] = e; __syncthreads();
  for (int off = 64; off > 0; off >>= 1) {
    if (t < off) red[t] += red[t + off];
    __syncthreads();
  }
  attn_out[b * S + t] = e / red[0];
}

// ---------------- K3: context partials over s-chunks ------------------------
__global__ __launch_bounds__(256) void k_ctx(
    const float* __restrict__ enc, const float* __restrict__ aw_in,
    float* __restrict__ ctxp) {
  __shared__ float aw[32];
  int b = blockIdx.x, sq = blockIdx.y, t = threadIdx.x;
  if (t < 32) aw[t] = aw_in[b * S + sq * 32 + t];
  __syncthreads();
  const float4* e4 = (const float4*)enc;
  float4 acc = {0.f, 0.f, 0.f, 0.f};
  for (int s = 0; s < 32; ++s) {
    float a = aw[s];
    float4 v = e4[(long long)(b * S + sq * 32 + s) * (H / 4) + t];
    acc.x += a * v.x; acc.y += a * v.y; acc.z += a * v.z; acc.w += a * v.w;
  }
  ((float4*)ctxp)[(long long)(sq * B + b) * (H / 4) + t] = acc;
}

// ---------------- K4: assemble xcat = [emb_gather | context] ----------------
__global__ __launch_bounds__(256) void k_xcat(
    const float* __restrict__ ctxp, const float* __restrict__ emb,
    const int* __restrict__ idx, float* __restrict__ xcat) {
  int ft = blockIdx.x * 256 + threadIdx.x;   // [0, B*H/4)
  int b = ft >> 8, hq = ft & 255;
  const float4* c4 = (const float4*)ctxp;
  float4 ctx = c4[(0 * B + b) * 256 + hq];
#pragma unroll
  for (int sq = 1; sq < 4; ++sq) {
    float4 v = c4[(sq * B + b) * 256 + hq];
    ctx.x += v.x; ctx.y += v.y; ctx.z += v.z; ctx.w += v.w;
  }
  float4* x4 = (float4*)xcat;
  x4[b * 512 + hq]       = ((const float4*)emb)[(long long)idx[b] * 256 + hq];
  x4[b * 512 + 256 + hq] = ctx;
}

// ------- K5/K7: C_tile[64g x 64b] = W[g,:] . X[b,:] over K-chunk ------------
// grid.x: g-tile, grid.y: K-split (dst advanced by 64*ldo per split slot)
__global__ __launch_bounds__(256) void k_gemm64(
    const float* __restrict__ W, int ldw,
    const float* __restrict__ X, int ldx,
    int KC, float* __restrict__ dst, int ldo,
    const float* __restrict__ bias) {
  __shared__ float Wl[16][64];
  __shared__ float Xl[16][64];
  int t = threadIdx.x;
  int g0 = blockIdx.x * 64;
  int k0 = blockIdx.y * KC;
  dst += (long long)blockIdx.y * 64 * ldo;
  int r = t >> 2, kw = (t & 3) * 4;     // staging: row (g or b), k-offset
  int gq = t >> 4, bq = t & 15;         // compute: 4g x 4b per thread
  float acc[4][4] = {};
  for (int kt = 0; kt < KC; kt += 16) {
    float4 wv4 = *(const float4*)(W + (long long)(g0 + r) * ldw + k0 + kt + kw);
    float4 xv4 = *(const float4*)(X + (long long)r * ldx + k0 + kt + kw);
    __syncthreads();
    Wl[kw + 0][r] = wv4.x; Wl[kw + 1][r] = wv4.y;
    Wl[kw + 2][r] = wv4.z; Wl[kw + 3][r] = wv4.w;
    Xl[kw + 0][r] = xv4.x; Xl[kw + 1][r] = xv4.y;
    Xl[kw + 2][r] = xv4.z; Xl[kw + 3][r] = xv4.w;
    __syncthreads();
#pragma unroll
    for (int kk = 0; kk < 16; ++kk) {
      float4 wv = *(const float4*)&Wl[kk][gq * 4];
      float4 xv = *(const float4*)&Xl[kk][bq * 4];
      acc[0][0] += wv.x * xv.x; acc[0][1] += wv.x * xv.y;
      acc[0][2] += wv.x * xv.z; acc[0][3] += wv.x * xv.w;
      acc[1][0] += wv.y * xv.x; acc[1][1] += wv.y * xv.y;
      acc[1][2] += wv.y * xv.z; acc[1][3] += wv.y * xv.w;
      acc[2][0] += wv.z * xv.x; acc[2][1] += wv.z * xv.y;
      acc[2][2] += wv.z * xv.z; acc[2][3] += wv.z * xv.w;
      acc[3][0] += wv.w * xv.x; acc[3][1] += wv.w * xv.y;
      acc[3][2] += wv.w * xv.z; acc[3][3] += wv.w * xv.w;
    }
  }
  float4 bs = {0.f, 0.f, 0.f, 0.f};
  if (bias) bs = *(const float4*)(bias + g0 + gq * 4);
#pragma unroll
  for (int j = 0; j < 4; ++j) {
    float4 o;
    o.x = acc[0][j] + bs.x; o.y = acc[1][j] + bs.y;
    o.z = acc[2][j] + bs.z; o.w = acc[3][j] + bs.w;
    *(float4*)(dst + (long long)(bq * 4 + j) * ldo + g0 + gq * 4) = o;
  }
}

// ---------------- K6: sum split-K partials, LSTM cell, mask -----------------
__global__ __launch_bounds__(256) void k_lstm(
    const float* __restrict__ part, const float* __restrict__ b_ih,
    const float* __restrict__ b_hh, const float* __restrict__ c0,
    const int* __restrict__ lengths,
    float* __restrict__ h1, float* __restrict__ c1) {
  int ft = blockIdx.x * 256 + threadIdx.x;   // [0, B*H)
  int b = ft >> 10, h = ft & 1023;
  float gs[4] = {0.f, 0.f, 0.f, 0.f};
  for (int ks = 0; ks < 6; ++ks) {
    const float* p = part + (long long)(ks * B + b) * 4096;
#pragma unroll
    for (int q = 0; q < 4; ++q) gs[q] += p[q * H + h];
  }
#pragma unroll
  for (int q = 0; q < 4; ++q) gs[q] += b_ih[q * H + h] + b_hh[q * H + h];
  float ig = 1.f / (1.f + expf(-gs[0]));
  float fg = 1.f / (1.f + expf(-gs[1]));
  float gg = tanhf(gs[2]);
  float og = 1.f / (1.f + expf(-gs[3]));
  float c = fg * c0[ft] + ig * gg;
  float hh = og * tanhf(c);
  if (lengths[b] == 0) { c = 0.f; hh = 0.f; }
  h1[ft] = hh; c1[ft] = c;
}

// ---------------- K8: per-(row, chunk) max + sumexp partials ----------------
__global__ __launch_bounds__(256) void k_lsm_part(
    const float* __restrict__ logits, float* __restrict__ pm,
    float* __restrict__ pl) {
  __shared__ float red[256];
  int b = blockIdx.x >> 3, q = blockIdx.x & 7, t = threadIdx.x;
  const float* row = logits + (long long)b * V + q * 4000;
  float v[16];
  float m = -INFINITY;
#pragma unroll
  for (int i = 0; i < 16; ++i) {
    int ii = t + 256 * i;
    v[i] = (ii < 4000) ? row[ii] : -INFINITY;
    m = fmaxf(m, v[i]);
  }
  red[t] = m; __syncthreads();
  for (int off = 128; off; off >>= 1) {
    if (t < off) red[t] = fmaxf(red[t], red[t + off]);
    __syncthreads();
  }
  float M = red[0]; __syncthreads();
  float s = 0.f;
#pragma unroll
  for (int i = 0; i < 16; ++i)
    s += (v[i] == -INFINITY) ? 0.f : expf(v[i] - M);
  red[t] = s; __syncthreads();
  for (int off = 128; off; off >>= 1) {
    if (t < off) red[t] += red[t + off];
    __syncthreads();
  }
  if (t == 0) { pm[blockIdx.x] = M; pl[blockIdx.x] = red[0]; }
}

// ---------------- K9: combine 8 partials per row -> M + log(L) --------------
__global__ __launch_bounds__(64) void k_lsm_comb(
    const float* __restrict__ pm, const float* __restrict__ pl,
    float* __restrict__ lc) {
  int b = threadIdx.x;   // 64 threads
  float M = -INFINITY;
  for (int q = 0; q < 8; ++q) M = fmaxf(M, pm[b * 8 + q]);
  float L = 0.f;
  for (int q = 0; q < 8; ++q) L += pl[b * 8 + q] * expf(pm[b * 8 + q] - M);
  lc[b] = M + logf(L);
}

// ---------------- K10: logprobs = logits - lc[b], in place ------------------
__global__ __launch_bounds__(256) void k_lsm_fin(
    float* __restrict__ logits, const float* __restrict__ lc) {
  int fi = blockIdx.x * 256 + threadIdx.x;   // float4 index, < 512000
  float4* p = (float4*)logits;
  float4 x = p[fi];
  float c = lc[fi / 8000];                   // 8000 float4 per row
  x.x -= c; x.y -= c; x.z -= c; x.w -= c;
  p[fi] = x;
}

extern "C" void kernel_launch(void* const* d_in, const int* in_sizes, int n_in,
                              void* d_out, int out_size, void* d_ws, size_t ws_size,
                              hipStream_t stream) {
  const int*   input_batch = (const int*)d_in[0];
  const float* prev_h = (const float*)d_in[1];
  const float* prev_c = (const float*)d_in[2];
  const float* enc    = (const float*)d_in[3];
  const int*   lengths= (const int*)d_in[4];
  const float* emb    = (const float*)d_in[5];
  const float* attn_w = (const float*)d_in[6];
  const float* attn_b = (const float*)d_in[7];
  const float* W_ih   = (const float*)d_in[8];
  const float* W_hh   = (const float*)d_in[9];
  const float* b_ih   = (const float*)d_in[10];
  const float* b_hh   = (const float*)d_in[11];
  const float* W_out  = (const float*)d_in[12];
  const float* b_out  = (const float*)d_in[13];

  float* out = (float*)d_out;
  float* ws  = (float*)d_ws;

  float* scores = ws + WS_SCORES;
  float* xcat   = ws + WS_XCAT;
  float* part   = ws + WS_PART;
  float* ctxp   = ws + WS_CTXP;
  float* pm     = ws + WS_PM;
  float* pl     = ws + WS_PL;
  float* lc     = ws + WS_LC;

  float* logits = out;             // logprobs region, used as logits scratch
  float* h1     = out + OUT_H1;
  float* c1     = out + OUT_C1;
  float* attn   = out + OUT_ATTN;

  // attention
  k_scores <<<dim3(B * S / 4), 256, 0, stream>>>(enc, attn_w, scores);
  k_softmax<<<dim3(B),         128, 0, stream>>>(scores, prev_h, attn_w, attn_b, attn);
  k_ctx    <<<dim3(B, 4),      256, 0, stream>>>(enc, attn, ctxp);
  k_xcat   <<<dim3(B * H / 1024), 256, 0, stream>>>(ctxp, emb, input_batch, xcat);

  // gates = xcat @ W_ih^T (split-K 4) + h0 @ W_hh^T (split-K 2) -> 6 partials
  k_gemm64 <<<dim3(64, 4), 256, 0, stream>>>(W_ih, KX, xcat, KX, 512,
                                             part, 4096, nullptr);
  k_gemm64 <<<dim3(64, 2), 256, 0, stream>>>(W_hh, H, prev_h, H, 512,
                                             part + 4LL * B * 4096, 4096, nullptr);
  k_lstm   <<<dim3(B * H / 256), 256, 0, stream>>>(part, b_ih, b_hh, prev_c,
                                                   lengths, h1, c1);

  // logits = h1 @ W_out^T + b_out (written straight into d_out)
  k_gemm64 <<<dim3(V / 64, 1), 256, 0, stream>>>(W_out, H, h1, H, H,
                                                 logits, V, b_out);

  // log-softmax over V, in place
  k_lsm_part<<<dim3(B * 8), 256, 0, stream>>>(logits, pm, pl);
  k_lsm_comb<<<dim3(1),      64, 0, stream>>>(pm, pl, lc);
  k_lsm_fin <<<dim3(B * V / 4 / 256), 256, 0, stream>>>(logits, lc);
}

// Round 2
// 360.496 us; speedup vs baseline: 1.2832x; 1.2832x over previous
//
#include <hip/hip_runtime.h>
#include <math.h>

constexpr int V = 32000, H = 1024, E = 1024, B = 64, S = 128;
constexpr int KX = 2048;                      // xcat = [emb | context]

// d_out offsets (floats), return order: logprobs, h1, c1, attn_weights
constexpr long long OUT_H1   = (long long)B * V;      // 2048000
constexpr long long OUT_C1   = OUT_H1 + (long long)B * H;
constexpr long long OUT_ATTN = OUT_C1 + (long long)B * H;

// ws offsets (floats)
constexpr long long WS_SCORES = 0;                                  // B*S
constexpr long long WS_XCAT   = WS_SCORES + (long long)B * S;       // B*2048
constexpr long long WS_PART   = WS_XCAT + (long long)B * KX;        // 6*B*4096
constexpr long long WS_CTXP   = WS_PART + 6LL * B * 4096;           // 4*B*H
constexpr long long WS_PM     = WS_CTXP + 4LL * B * H;              // 512
constexpr long long WS_PL     = WS_PM + 512;                        // 512
constexpr long long WS_LC     = WS_PL + 512;                        // 64

typedef __attribute__((ext_vector_type(8))) short short8;
typedef __attribute__((ext_vector_type(4))) float f32x4;

__device__ __forceinline__ unsigned short f2bf(float f) {
  unsigned u = __float_as_uint(f);
  u += 0x7FFF + ((u >> 16) & 1);          // round-to-nearest-even
  return (unsigned short)(u >> 16);
}

__device__ __forceinline__ short8 pack8(float4 a, float4 b) {
  short8 s;
  s[0] = (short)f2bf(a.x); s[1] = (short)f2bf(a.y);
  s[2] = (short)f2bf(a.z); s[3] = (short)f2bf(a.w);
  s[4] = (short)f2bf(b.x); s[5] = (short)f2bf(b.y);
  s[6] = (short)f2bf(b.z); s[7] = (short)f2bf(b.w);
  return s;
}

// ---- MFMA GEMM body: dst[b, g0+g] (+bias) = sum_k W[g0+g, k0+k] X[b, k0+k] -
// 64(g) x 64(b) tile per block, bf16 16x16x32 MFMA, fp32->bf16 in registers.
// LDS: bf16 tiles, row stride 64, 8-bf16 chunks XOR-swizzled by (row&7).
__device__ __forceinline__ void gemm_body(
    const float* __restrict__ W, int ldw,
    const float* __restrict__ X, int ldx,
    int g0, int k0, int KC,
    float* __restrict__ dst, int ldo, const float* __restrict__ bias) {
  __shared__ __align__(16) unsigned short Wl[64 * 64];
  __shared__ __align__(16) unsigned short Xl[64 * 64];
  int t = threadIdx.x;
  int lane = t & 63, wid = t >> 6;
  int n = lane & 15, quad = lane >> 4;
  // staging: 512 chunks (8 bf16) per tile, 2 per thread
  int r0 = t >> 3,          c0 = t & 7;
  int r1 = (t + 256) >> 3,  c1 = (t + 256) & 7;
  int ws0 = r0 * 64 + (c0 ^ (r0 & 7)) * 8;
  int ws1 = r1 * 64 + (c1 ^ (r1 & 7)) * 8;
  f32x4 acc[4] = {{0.f,0.f,0.f,0.f},{0.f,0.f,0.f,0.f},
                  {0.f,0.f,0.f,0.f},{0.f,0.f,0.f,0.f}};
  const float* Wg = W + (long long)g0 * ldw + k0;
  const float* Xg = X + k0;

  for (int kt = 0; kt < KC; kt += 64) {
    const float4* wp0 = (const float4*)(Wg + (long long)r0 * ldw + kt + c0 * 8);
    const float4* wp1 = (const float4*)(Wg + (long long)r1 * ldw + kt + c1 * 8);
    const float4* xp0 = (const float4*)(Xg + (long long)r0 * ldx + kt + c0 * 8);
    const float4* xp1 = (const float4*)(Xg + (long long)r1 * ldx + kt + c1 * 8);
    float4 wa = wp0[0], wb = wp0[1];
    float4 wc = wp1[0], wd = wp1[1];
    float4 xa = xp0[0], xb = xp0[1];
    float4 xc = xp1[0], xd = xp1[1];
    __syncthreads();                       // prior compute reads done
    *(short8*)&Wl[ws0] = pack8(wa, wb);
    *(short8*)&Wl[ws1] = pack8(wc, wd);
    *(short8*)&Xl[ws0] = pack8(xa, xb);
    *(short8*)&Xl[ws1] = pack8(xc, xd);
    __syncthreads();
#pragma unroll
    for (int kc = 0; kc < 2; ++kc) {
      short8 af = *(const short8*)&Wl[(wid * 16 + n) * 64 +
                                      (((kc * 4 + quad) ^ (n & 7)) * 8)];
#pragma unroll
      for (int nt = 0; nt < 4; ++nt) {
        short8 bf = *(const short8*)&Xl[(nt * 16 + n) * 64 +
                                        (((kc * 4 + quad) ^ (n & 7)) * 8)];
        acc[nt] = __builtin_amdgcn_mfma_f32_16x16x32_bf16(af, bf, acc[nt], 0, 0, 0);
      }
    }
  }
  // epilogue: C/D layout col=lane&15 (b), row=quad*4+reg (g-local)
  int gl = wid * 16 + quad * 4;
  float bs[4] = {0.f, 0.f, 0.f, 0.f};
  if (bias) {
#pragma unroll
    for (int r = 0; r < 4; ++r) bs[r] = bias[g0 + gl + r];
  }
#pragma unroll
  for (int nt = 0; nt < 4; ++nt) {
    int b = nt * 16 + n;
#pragma unroll
    for (int r = 0; r < 4; ++r)
      dst[(long long)b * ldo + g0 + gl + r] = acc[nt][r] + bs[r];
  }
}

// gates: grid (64, 6). y<4: W_ih K-split 4; y>=4: W_hh K-split 2.
__global__ __launch_bounds__(256) void k_gates_mfma(
    const float* __restrict__ W_ih, const float* __restrict__ xcat,
    const float* __restrict__ W_hh, const float* __restrict__ h0,
    float* __restrict__ part) {
  int y = blockIdx.y;
  if (y < 4)
    gemm_body(W_ih, KX, xcat, KX, blockIdx.x * 64, y * 512, 512,
              part + (long long)y * B * 4096, 4096, nullptr);
  else
    gemm_body(W_hh, H, h0, H, blockIdx.x * 64, (y - 4) * 512, 512,
              part + (long long)y * B * 4096, 4096, nullptr);
}

// logits: grid (500). dst = logits [b][V], bias = b_out.
__global__ __launch_bounds__(256) void k_logits_mfma(
    const float* __restrict__ W_out, const float* __restrict__ h1,
    float* __restrict__ logits, const float* __restrict__ b_out) {
  gemm_body(W_out, H, h1, H, blockIdx.x * 64, 0, H, logits, V, b_out);
}

// ---------------- K1: e_part[b,s] = dot(enc[b,s,:], attn_w[H:]) -------------
__global__ __launch_bounds__(256) void k_scores(
    const float* __restrict__ enc, const float* __restrict__ attn_w,
    float* __restrict__ scores) {
  int w = (blockIdx.x * 256 + threadIdx.x) >> 6;   // (b*S+s) in [0, 8192)
  int lane = threadIdx.x & 63;
  const float4* e4 = (const float4*)(enc + (long long)w * H);
  const float4* w4 = (const float4*)(attn_w + H);
  float acc = 0.f;
#pragma unroll
  for (int i = 0; i < 4; ++i) {
    float4 a = e4[lane + 64 * i];
    float4 b = w4[lane + 64 * i];
    acc += a.x * b.x + a.y * b.y + a.z * b.z + a.w * b.w;
  }
#pragma unroll
  for (int m = 32; m; m >>= 1) acc += __shfl_xor(acc, m, 64);
  if (lane == 0) scores[w] = acc;
}

// ---------------- K2: h_part + softmax over S, write attn weights -----------
__global__ __launch_bounds__(128) void k_softmax(
    const float* __restrict__ scores, const float* __restrict__ h0,
    const float* __restrict__ attn_w, const float* __restrict__ attn_b,
    float* __restrict__ attn_out) {
  __shared__ float red[128];
  int b = blockIdx.x, t = threadIdx.x;
  float p = 0.f;
#pragma unroll
  for (int j = 0; j < 8; ++j) {
    int k = t + 128 * j;
    p += h0[b * H + k] * attn_w[k];
  }
  red[t] = p; __syncthreads();
  for (int off = 64; off > 0; off >>= 1) {
    if (t < off) red[t] += red[t + off];
    __syncthreads();
  }
  float hp = red[0]; __syncthreads();
  float sc = scores[b * S + t] + hp + attn_b[0];
  red[t] = sc; __syncthreads();
  for (int off = 64; off > 0; off >>= 1) {
    if (t < off) red[t] = fmaxf(red[t], red[t + off]);
    __syncthreads();
  }
  float m = red[0]; __syncthreads();
  float e = expf(sc - m);
  red[t] = e; __syncthreads();
  for (int off = 64; off > 0; off >>= 1) {
    if (t < off) red[t] += red[t + off];
    __syncthreads();
  }
  attn_out[b * S + t] = e / red[0];
}

// ---------------- K3: context partials over s-chunks ------------------------
__global__ __launch_bounds__(256) void k_ctx(
    const float* __restrict__ enc, const float* __restrict__ aw_in,
    float* __restrict__ ctxp) {
  __shared__ float aw[32];
  int b = blockIdx.x, sq = blockIdx.y, t = threadIdx.x;
  if (t < 32) aw[t] = aw_in[b * S + sq * 32 + t];
  __syncthreads();
  const float4* e4 = (const float4*)enc;
  float4 acc = {0.f, 0.f, 0.f, 0.f};
  for (int s = 0; s < 32; ++s) {
    float a = aw[s];
    float4 v = e4[(long long)(b * S + sq * 32 + s) * (H / 4) + t];
    acc.x += a * v.x; acc.y += a * v.y; acc.z += a * v.z; acc.w += a * v.w;
  }
  ((float4*)ctxp)[(long long)(sq * B + b) * (H / 4) + t] = acc;
}

// ---------------- K4: assemble xcat = [emb_gather | context] ----------------
__global__ __launch_bounds__(256) void k_xcat(
    const float* __restrict__ ctxp, const float* __restrict__ emb,
    const int* __restrict__ idx, float* __restrict__ xcat) {
  int ft = blockIdx.x * 256 + threadIdx.x;   // [0, B*H/4)
  int b = ft >> 8, hq = ft & 255;
  const float4* c4 = (const float4*)ctxp;
  float4 ctx = c4[(0 * B + b) * 256 + hq];
#pragma unroll
  for (int sq = 1; sq < 4; ++sq) {
    float4 v = c4[(sq * B + b) * 256 + hq];
    ctx.x += v.x; ctx.y += v.y; ctx.z += v.z; ctx.w += v.w;
  }
  float4* x4 = (float4*)xcat;
  x4[b * 512 + hq]       = ((const float4*)emb)[(long long)idx[b] * 256 + hq];
  x4[b * 512 + 256 + hq] = ctx;
}

// ---------------- K6: sum split-K partials, LSTM cell, mask -----------------
__global__ __launch_bounds__(256) void k_lstm(
    const float* __restrict__ part, const float* __restrict__ b_ih,
    const float* __restrict__ b_hh, const float* __restrict__ c0,
    const int* __restrict__ lengths,
    float* __restrict__ h1, float* __restrict__ c1) {
  int ft = blockIdx.x * 256 + threadIdx.x;   // [0, B*H)
  int b = ft >> 10, h = ft & 1023;
  float gs[4] = {0.f, 0.f, 0.f, 0.f};
  for (int ks = 0; ks < 6; ++ks) {
    const float* p = part + (long long)(ks * B + b) * 4096;
#pragma unroll
    for (int q = 0; q < 4; ++q) gs[q] += p[q * H + h];
  }
#pragma unroll
  for (int q = 0; q < 4; ++q) gs[q] += b_ih[q * H + h] + b_hh[q * H + h];
  float ig = 1.f / (1.f + expf(-gs[0]));
  float fg = 1.f / (1.f + expf(-gs[1]));
  float gg = tanhf(gs[2]);
  float og = 1.f / (1.f + expf(-gs[3]));
  float c = fg * c0[ft] + ig * gg;
  float hh = og * tanhf(c);
  if (lengths[b] == 0) { c = 0.f; hh = 0.f; }
  h1[ft] = hh; c1[ft] = c;
}

// ---------------- K8: per-(row, chunk) max + sumexp partials ----------------
__global__ __launch_bounds__(256) void k_lsm_part(
    const float* __restrict__ logits, float* __restrict__ pm,
    float* __restrict__ pl) {
  __shared__ float red[256];
  int b = blockIdx.x >> 3, q = blockIdx.x & 7, t = threadIdx.x;
  const float* row = logits + (long long)b * V + q * 4000;
  float v[16];
  float m = -INFINITY;
#pragma unroll
  for (int i = 0; i < 16; ++i) {
    int ii = t + 256 * i;
    v[i] = (ii < 4000) ? row[ii] : -INFINITY;
    m = fmaxf(m, v[i]);
  }
  red[t] = m; __syncthreads();
  for (int off = 128; off; off >>= 1) {
    if (t < off) red[t] = fmaxf(red[t], red[t + off]);
    __syncthreads();
  }
  float M = red[0]; __syncthreads();
  float s = 0.f;
#pragma unroll
  for (int i = 0; i < 16; ++i)
    s += (v[i] == -INFINITY) ? 0.f : expf(v[i] - M);
  red[t] = s; __syncthreads();
  for (int off = 128; off; off >>= 1) {
    if (t < off) red[t] += red[t + off];
    __syncthreads();
  }
  if (t == 0) { pm[blockIdx.x] = M; pl[blockIdx.x] = red[0]; }
}

// ---------------- K9: combine 8 partials per row -> M + log(L) --------------
__global__ __launch_bounds__(64) void k_lsm_comb(
    const float* __restrict__ pm, const float* __restrict__ pl,
    float* __restrict__ lc) {
  int b = threadIdx.x;   // 64 threads
  float M = -INFINITY;
  for (int q = 0; q < 8; ++q) M = fmaxf(M, pm[b * 8 + q]);
  float L = 0.f;
  for (int q = 0; q < 8; ++q) L += pl[b * 8 + q] * expf(pm[b * 8 + q] - M);
  lc[b] = M + logf(L);
}

// ---------------- K10: logprobs = logits - lc[b], in place ------------------
__global__ __launch_bounds__(256) void k_lsm_fin(
    float* __restrict__ logits, const float* __restrict__ lc) {
  int fi = blockIdx.x * 256 + threadIdx.x;   // float4 index, < 512000
  float4* p = (float4*)logits;
  float4 x = p[fi];
  float c = lc[fi / 8000];                   // 8000 float4 per row
  x.x -= c; x.y -= c; x.z -= c; x.w -= c;
  p[fi] = x;
}

extern "C" void kernel_launch(void* const* d_in, const int* in_sizes, int n_in,
                              void* d_out, int out_size, void* d_ws, size_t ws_size,
                              hipStream_t stream) {
  const int*   input_batch = (const int*)d_in[0];
  const float* prev_h = (const float*)d_in[1];
  const float* prev_c = (const float*)d_in[2];
  const float* enc    = (const float*)d_in[3];
  const int*   lengths= (const int*)d_in[4];
  const float* emb    = (const float*)d_in[5];
  const float* attn_w = (const float*)d_in[6];
  const float* attn_b = (const float*)d_in[7];
  const float* W_ih   = (const float*)d_in[8];
  const float* W_hh   = (const float*)d_in[9];
  const float* b_ih   = (const float*)d_in[10];
  const float* b_hh   = (const float*)d_in[11];
  const float* W_out  = (const float*)d_in[12];
  const float* b_out  = (const float*)d_in[13];

  float* out = (float*)d_out;
  float* ws  = (float*)d_ws;

  float* scores = ws + WS_SCORES;
  float* xcat   = ws + WS_XCAT;
  float* part   = ws + WS_PART;
  float* ctxp   = ws + WS_CTXP;
  float* pm     = ws + WS_PM;
  float* pl     = ws + WS_PL;
  float* lc     = ws + WS_LC;

  float* logits = out;             // logprobs region, used as logits scratch
  float* h1     = out + OUT_H1;
  float* c1     = out + OUT_C1;
  float* attn   = out + OUT_ATTN;

  // attention
  k_scores <<<dim3(B * S / 4), 256, 0, stream>>>(enc, attn_w, scores);
  k_softmax<<<dim3(B),         128, 0, stream>>>(scores, prev_h, attn_w, attn_b, attn);
  k_ctx    <<<dim3(B, 4),      256, 0, stream>>>(enc, attn, ctxp);
  k_xcat   <<<dim3(B * H / 1024), 256, 0, stream>>>(ctxp, emb, input_batch, xcat);

  // gates = xcat @ W_ih^T (split-K 4) + h0 @ W_hh^T (split-K 2) -> 6 partials
  k_gates_mfma<<<dim3(64, 6), 256, 0, stream>>>(W_ih, xcat, W_hh, prev_h, part);
  k_lstm   <<<dim3(B * H / 256), 256, 0, stream>>>(part, b_ih, b_hh, prev_c,
                                                   lengths, h1, c1);

  // logits = h1 @ W_out^T + b_out (written straight into d_out)
  k_logits_mfma<<<dim3(V / 64), 256, 0, stream>>>(W_out, h1, logits, b_out);

  // log-softmax over V, in place
  k_lsm_part<<<dim3(B * 8), 256, 0, stream>>>(logits, pm, pl);
  k_lsm_comb<<<dim3(1),      64, 0, stream>>>(pm, pl, lc);
  k_lsm_fin <<<dim3(B * V / 4 / 256), 256, 0, stream>>>(logits, lc);
}

// Round 3
// 352.025 us; speedup vs baseline: 1.3141x; 1.0241x over previous
//
#include <hip/hip_runtime.h>
#include <math.h>

constexpr int V = 32000, H = 1024, E = 1024, B = 64, S = 128;
constexpr int KX = 2048;                      // xcat = [emb | context]

// d_out offsets (floats), return order: logprobs, h1, c1, attn_weights
constexpr long long OUT_H1   = (long long)B * V;      // 2048000
constexpr long long OUT_C1   = OUT_H1 + (long long)B * H;
constexpr long long OUT_ATTN = OUT_C1 + (long long)B * H;

// ws offsets (floats)
constexpr long long WS_SCORES = 0;                                  // B*S
constexpr long long WS_XCAT   = WS_SCORES + (long long)B * S;       // B*2048
constexpr long long WS_PART   = WS_XCAT + (long long)B * KX;        // 6*B*4096
constexpr long long WS_CTXP   = WS_PART + 6LL * B * 4096;           // 4*B*H
constexpr long long WS_PM     = WS_CTXP + 4LL * B * H;              // 64*512
constexpr long long WS_PL     = WS_PM + 64 * 512;                   // 64*512
constexpr long long WS_LC     = WS_PL + 64 * 512;                   // 64

typedef __attribute__((ext_vector_type(8))) short short8;
typedef __attribute__((ext_vector_type(4))) float f32x4;

__device__ __forceinline__ unsigned short f2bf(float f) {
  unsigned u = __float_as_uint(f);
  u += 0x7FFF + ((u >> 16) & 1);          // round-to-nearest-even
  return (unsigned short)(u >> 16);
}

__device__ __forceinline__ short8 pack8(float4 a, float4 b) {
  short8 s;
  s[0] = (short)f2bf(a.x); s[1] = (short)f2bf(a.y);
  s[2] = (short)f2bf(a.z); s[3] = (short)f2bf(a.w);
  s[4] = (short)f2bf(b.x); s[5] = (short)f2bf(b.y);
  s[6] = (short)f2bf(b.z); s[7] = (short)f2bf(b.w);
  return s;
}

// ---- MFMA GEMM body: dst[b, g0+g] (+bias) = sum_k W[g0+g, k0+k] X[b, k0+k] -
// 64(g) x 64(b) tile per block, bf16 16x16x32 MFMA, fp32->bf16 in registers.
// Software-pipelined: K-tile kt+1 global loads issued before MFMA phase of kt.
// LDS: bf16 tiles, row stride 64, 8-bf16 chunks XOR-swizzled by (row&7).
// If pm != nullptr: also emit per-block log-softmax partials over the 64
// g-rows (pm[b*512+blk] = max, pl[b*512+blk] = sum exp(v - max)).
__device__ __forceinline__ void gemm_body(
    const float* __restrict__ W, int ldw,
    const float* __restrict__ X, int ldx,
    int g0, int k0, int KC,
    float* __restrict__ dst, int ldo, const float* __restrict__ bias,
    float* __restrict__ pm, float* __restrict__ pl) {
  __shared__ __align__(16) unsigned short Wl[64 * 64];
  __shared__ __align__(16) unsigned short Xl[64 * 64];
  __shared__ float pmx[4][64];
  __shared__ float psm[4][64];
  int t = threadIdx.x;
  int lane = t & 63, wid = t >> 6;
  int n = lane & 15, quad = lane >> 4;
  // staging: 512 chunks (8 bf16) per tile, 2 per thread
  int r0 = t >> 3,          c0 = t & 7;
  int r1 = (t + 256) >> 3,  c1 = (t + 256) & 7;
  int ws0 = r0 * 64 + (c0 ^ (r0 & 7)) * 8;
  int ws1 = r1 * 64 + (c1 ^ (r1 & 7)) * 8;
  f32x4 acc[4] = {{0.f,0.f,0.f,0.f},{0.f,0.f,0.f,0.f},
                  {0.f,0.f,0.f,0.f},{0.f,0.f,0.f,0.f}};
  const float* wp0 = W + (long long)(g0 + r0) * ldw + k0 + c0 * 8;
  const float* wp1 = W + (long long)(g0 + r1) * ldw + k0 + c1 * 8;
  const float* xp0 = X + (long long)r0 * ldx + k0 + c0 * 8;
  const float* xp1 = X + (long long)r1 * ldx + k0 + c1 * 8;
  // prefetch K-tile 0
  float4 wa = ((const float4*)wp0)[0], wb = ((const float4*)wp0)[1];
  float4 wc = ((const float4*)wp1)[0], wd = ((const float4*)wp1)[1];
  float4 xa = ((const float4*)xp0)[0], xb = ((const float4*)xp0)[1];
  float4 xc = ((const float4*)xp1)[0], xd = ((const float4*)xp1)[1];

  for (int kt = 0; kt < KC; kt += 64) {
    __syncthreads();                       // prior compute's LDS reads done
    *(short8*)&Wl[ws0] = pack8(wa, wb);
    *(short8*)&Wl[ws1] = pack8(wc, wd);
    *(short8*)&Xl[ws0] = pack8(xa, xb);
    *(short8*)&Xl[ws1] = pack8(xc, xd);
    __syncthreads();
    if (kt + 64 < KC) {                    // issue next tile's loads now;
      int o = kt + 64;                     // consumed at next LDS write
      wa = *(const float4*)(wp0 + o); wb = *(const float4*)(wp0 + o + 4);
      wc = *(const float4*)(wp1 + o); wd = *(const float4*)(wp1 + o + 4);
      xa = *(const float4*)(xp0 + o); xb = *(const float4*)(xp0 + o + 4);
      xc = *(const float4*)(xp1 + o); xd = *(const float4*)(xp1 + o + 4);
    }
#pragma unroll
    for (int kc = 0; kc < 2; ++kc) {
      short8 af = *(const short8*)&Wl[(wid * 16 + n) * 64 +
                                      (((kc * 4 + quad) ^ (n & 7)) * 8)];
#pragma unroll
      for (int nt = 0; nt < 4; ++nt) {
        short8 bf = *(const short8*)&Xl[(nt * 16 + n) * 64 +
                                        (((kc * 4 + quad) ^ (n & 7)) * 8)];
        acc[nt] = __builtin_amdgcn_mfma_f32_16x16x32_bf16(af, bf, acc[nt], 0, 0, 0);
      }
    }
  }
  // epilogue: C/D layout col=lane&15 (b), row=quad*4+reg (g-local)
  int gl = wid * 16 + quad * 4;
  float bs[4] = {0.f, 0.f, 0.f, 0.f};
  if (bias) {
#pragma unroll
    for (int r = 0; r < 4; ++r) bs[r] = bias[g0 + gl + r];
  }
  float v[4][4];
#pragma unroll
  for (int nt = 0; nt < 4; ++nt) {
    int b = nt * 16 + n;
#pragma unroll
    for (int r = 0; r < 4; ++r) {
      v[nt][r] = acc[nt][r] + bs[r];
      dst[(long long)b * ldo + g0 + gl + r] = v[nt][r];
    }
  }
  if (pm) {
    // per-block log-softmax partials over this block's 64 rows, per b
    float tmax[4];
#pragma unroll
    for (int nt = 0; nt < 4; ++nt) {
      tmax[nt] = fmaxf(fmaxf(v[nt][0], v[nt][1]), fmaxf(v[nt][2], v[nt][3]));
      tmax[nt] = fmaxf(tmax[nt], __shfl_xor(tmax[nt], 16, 64));
      tmax[nt] = fmaxf(tmax[nt], __shfl_xor(tmax[nt], 32, 64));
    }
    if (lane < 16) {
#pragma unroll
      for (int nt = 0; nt < 4; ++nt) pmx[wid][nt * 16 + lane] = tmax[nt];
    }
    __syncthreads();
    float bmax[4], tsum[4];
#pragma unroll
    for (int nt = 0; nt < 4; ++nt) {
      bmax[nt] = fmaxf(fmaxf(pmx[0][nt * 16 + n], pmx[1][nt * 16 + n]),
                       fmaxf(pmx[2][nt * 16 + n], pmx[3][nt * 16 + n]));
      tsum[nt] = __expf(v[nt][0] - bmax[nt]) + __expf(v[nt][1] - bmax[nt]) +
                 __expf(v[nt][2] - bmax[nt]) + __expf(v[nt][3] - bmax[nt]);
      tsum[nt] += __shfl_xor(tsum[nt], 16, 64);
      tsum[nt] += __shfl_xor(tsum[nt], 32, 64);
    }
    if (lane < 16) {
#pragma unroll
      for (int nt = 0; nt < 4; ++nt) psm[wid][nt * 16 + lane] = tsum[nt];
    }
    __syncthreads();
    if (t < 64) {
      float M = fmaxf(fmaxf(pmx[0][t], pmx[1][t]), fmaxf(pmx[2][t], pmx[3][t]));
      float L = psm[0][t] + psm[1][t] + psm[2][t] + psm[3][t];
      pm[t * 512 + blockIdx.x] = M;
      pl[t * 512 + blockIdx.x] = L;
    }
  }
}

// gates: grid (64, 6). y<4: W_ih K-split 4; y>=4: W_hh K-split 2.
__global__ __launch_bounds__(256) void k_gates_mfma(
    const float* __restrict__ W_ih, const float* __restrict__ xcat,
    const float* __restrict__ W_hh, const float* __restrict__ h0,
    float* __restrict__ part) {
  int y = blockIdx.y;
  if (y < 4)
    gemm_body(W_ih, KX, xcat, KX, blockIdx.x * 64, y * 512, 512,
              part + (long long)y * B * 4096, 4096, nullptr, nullptr, nullptr);
  else
    gemm_body(W_hh, H, h0, H, blockIdx.x * 64, (y - 4) * 512, 512,
              part + (long long)y * B * 4096, 4096, nullptr, nullptr, nullptr);
}

// logits: grid (500). dst = logits [b][V], bias = b_out, + lsm partials.
__global__ __launch_bounds__(256) void k_logits_mfma(
    const float* __restrict__ W_out, const float* __restrict__ h1,
    float* __restrict__ logits, const float* __restrict__ b_out,
    float* __restrict__ pm, float* __restrict__ pl) {
  gemm_body(W_out, H, h1, H, blockIdx.x * 64, 0, H, logits, V, b_out, pm, pl);
}

// ---------------- K1: e_part[b,s] = dot(enc[b,s,:], attn_w[H:]) -------------
__global__ __launch_bounds__(256) void k_scores(
    const float* __restrict__ enc, const float* __restrict__ attn_w,
    float* __restrict__ scores) {
  int w = (blockIdx.x * 256 + threadIdx.x) >> 6;   // (b*S+s) in [0, 8192)
  int lane = threadIdx.x & 63;
  const float4* e4 = (const float4*)(enc + (long long)w * H);
  const float4* w4 = (const float4*)(attn_w + H);
  float acc = 0.f;
#pragma unroll
  for (int i = 0; i < 4; ++i) {
    float4 a = e4[lane + 64 * i];
    float4 b = w4[lane + 64 * i];
    acc += a.x * b.x + a.y * b.y + a.z * b.z + a.w * b.w;
  }
#pragma unroll
  for (int m = 32; m; m >>= 1) acc += __shfl_xor(acc, m, 64);
  if (lane == 0) scores[w] = acc;
}

// ---------------- K2: h_part + softmax over S, write attn weights -----------
__global__ __launch_bounds__(128) void k_softmax(
    const float* __restrict__ scores, const float* __restrict__ h0,
    const float* __restrict__ attn_w, const float* __restrict__ attn_b,
    float* __restrict__ attn_out) {
  __shared__ float red[128];
  int b = blockIdx.x, t = threadIdx.x;
  float p = 0.f;
#pragma unroll
  for (int j = 0; j < 8; ++j) {
    int k = t + 128 * j;
    p += h0[b * H + k] * attn_w[k];
  }
  red[t] = p; __syncthreads();
  for (int off = 64; off > 0; off >>= 1) {
    if (t < off) red[t] += red[t + off];
    __syncthreads();
  }
  float hp = red[0]; __syncthreads();
  float sc = scores[b * S + t] + hp + attn_b[0];
  red[t] = sc; __syncthreads();
  for (int off = 64; off > 0; off >>= 1) {
    if (t < off) red[t] = fmaxf(red[t], red[t + off]);
    __syncthreads();
  }
  float m = red[0]; __syncthreads();
  float e = expf(sc - m);
  red[t] = e; __syncthreads();
  for (int off = 64; off > 0; off >>= 1) {
    if (t < off) red[t] += red[t + off];
    __syncthreads();
  }
  attn_out[b * S + t] = e / red[0];
}

// ---------------- K3: context partials over s-chunks ------------------------
__global__ __launch_bounds__(256) void k_ctx(
    const float* __restrict__ enc, const float* __restrict__ aw_in,
    float* __restrict__ ctxp) {
  __shared__ float aw[32];
  int b = blockIdx.x, sq = blockIdx.y, t = threadIdx.x;
  if (t < 32) aw[t] = aw_in[b * S + sq * 32 + t];
  __syncthreads();
  const float4* e4 = (const float4*)enc;
  float4 acc = {0.f, 0.f, 0.f, 0.f};
  for (int s = 0; s < 32; ++s) {
    float a = aw[s];
    float4 v = e4[(long long)(b * S + sq * 32 + s) * (H / 4) + t];
    acc.x += a * v.x; acc.y += a * v.y; acc.z += a * v.z; acc.w += a * v.w;
  }
  ((float4*)ctxp)[(long long)(sq * B + b) * (H / 4) + t] = acc;
}

// ---------------- K4: assemble xcat = [emb_gather | context] ----------------
__global__ __launch_bounds__(256) void k_xcat(
    const float* __restrict__ ctxp, const float* __restrict__ emb,
    const int* __restrict__ idx, float* __restrict__ xcat) {
  int ft = blockIdx.x * 256 + threadIdx.x;   // [0, B*H/4)
  int b = ft >> 8, hq = ft & 255;
  const float4* c4 = (const float4*)ctxp;
  float4 ctx = c4[(0 * B + b) * 256 + hq];
#pragma unroll
  for (int sq = 1; sq < 4; ++sq) {
    float4 v = c4[(sq * B + b) * 256 + hq];
    ctx.x += v.x; ctx.y += v.y; ctx.z += v.z; ctx.w += v.w;
  }
  float4* x4 = (float4*)xcat;
  x4[b * 512 + hq]       = ((const float4*)emb)[(long long)idx[b] * 256 + hq];
  x4[b * 512 + 256 + hq] = ctx;
}

// ---------------- K6: sum split-K partials, LSTM cell, mask -----------------
__global__ __launch_bounds__(256) void k_lstm(
    const float* __restrict__ part, const float* __restrict__ b_ih,
    const float* __restrict__ b_hh, const float* __restrict__ c0,
    const int* __restrict__ lengths,
    float* __restrict__ h1, float* __restrict__ c1) {
  int ft = blockIdx.x * 256 + threadIdx.x;   // [0, B*H)
  int b = ft >> 10, h = ft & 1023;
  float gs[4] = {0.f, 0.f, 0.f, 0.f};
  for (int ks = 0; ks < 6; ++ks) {
    const float* p = part + (long long)(ks * B + b) * 4096;
#pragma unroll
    for (int q = 0; q < 4; ++q) gs[q] += p[q * H + h];
  }
#pragma unroll
  for (int q = 0; q < 4; ++q) gs[q] += b_ih[q * H + h] + b_hh[q * H + h];
  float ig = 1.f / (1.f + expf(-gs[0]));
  float fg = 1.f / (1.f + expf(-gs[1]));
  float gg = tanhf(gs[2]);
  float og = 1.f / (1.f + expf(-gs[3]));
  float c = fg * c0[ft] + ig * gg;
  float hh = og * tanhf(c);
  if (lengths[b] == 0) { c = 0.f; hh = 0.f; }
  h1[ft] = hh; c1[ft] = c;
}

// ------ K9: combine 500 per-block partials per row -> lc[b] = M + log(L) ----
__global__ __launch_bounds__(256) void k_lsm_comb(
    const float* __restrict__ pm, const float* __restrict__ pl,
    float* __restrict__ lc) {
  __shared__ float red[256];
  int b = blockIdx.x, t = threadIdx.x;
  float v0 = pm[b * 512 + t];                       // t < 256 < 500: valid
  float v1 = (t + 256 < 500) ? pm[b * 512 + t + 256] : -INFINITY;
  red[t] = fmaxf(v0, v1); __syncthreads();
  for (int off = 128; off; off >>= 1) {
    if (t < off) red[t] = fmaxf(red[t], red[t + off]);
    __syncthreads();
  }
  float M = red[0]; __syncthreads();
  float s = pl[b * 512 + t] * __expf(v0 - M);
  if (t + 256 < 500) s += pl[b * 512 + t + 256] * __expf(v1 - M);
  red[t] = s; __syncthreads();
  for (int off = 128; off; off >>= 1) {
    if (t < off) red[t] += red[t + off];
    __syncthreads();
  }
  if (t == 0) lc[b] = M + logf(red[0]);
}

// ---------------- K10: logprobs = logits - lc[b], in place ------------------
__global__ __launch_bounds__(256) void k_lsm_fin(
    float* __restrict__ logits, const float* __restrict__ lc) {
  int fi = blockIdx.x * 256 + threadIdx.x;   // float4 index, < 512000
  float4* p = (float4*)logits;
  float4 x = p[fi];
  float c = lc[fi / 8000];                   // 8000 float4 per row
  x.x -= c; x.y -= c; x.z -= c; x.w -= c;
  p[fi] = x;
}

extern "C" void kernel_launch(void* const* d_in, const int* in_sizes, int n_in,
                              void* d_out, int out_size, void* d_ws, size_t ws_size,
                              hipStream_t stream) {
  const int*   input_batch = (const int*)d_in[0];
  const float* prev_h = (const float*)d_in[1];
  const float* prev_c = (const float*)d_in[2];
  const float* enc    = (const float*)d_in[3];
  const int*   lengths= (const int*)d_in[4];
  const float* emb    = (const float*)d_in[5];
  const float* attn_w = (const float*)d_in[6];
  const float* attn_b = (const float*)d_in[7];
  const float* W_ih   = (const float*)d_in[8];
  const float* W_hh   = (const float*)d_in[9];
  const float* b_ih   = (const float*)d_in[10];
  const float* b_hh   = (const float*)d_in[11];
  const float* W_out  = (const float*)d_in[12];
  const float* b_out  = (const float*)d_in[13];

  float* out = (float*)d_out;
  float* ws  = (float*)d_ws;

  float* scores = ws + WS_SCORES;
  float* xcat   = ws + WS_XCAT;
  float* part   = ws + WS_PART;
  float* ctxp   = ws + WS_CTXP;
  float* pm     = ws + WS_PM;
  float* pl     = ws + WS_PL;
  float* lc     = ws + WS_LC;

  float* logits = out;             // logprobs region, used as logits scratch
  float* h1     = out + OUT_H1;
  float* c1     = out + OUT_C1;
  float* attn   = out + OUT_ATTN;

  // attention
  k_scores <<<dim3(B * S / 4), 256, 0, stream>>>(enc, attn_w, scores);
  k_softmax<<<dim3(B),         128, 0, stream>>>(scores, prev_h, attn_w, attn_b, attn);
  k_ctx    <<<dim3(B, 4),      256, 0, stream>>>(enc, attn, ctxp);
  k_xcat   <<<dim3(B * H / 1024), 256, 0, stream>>>(ctxp, emb, input_batch, xcat);

  // gates = xcat @ W_ih^T (split-K 4) + h0 @ W_hh^T (split-K 2) -> 6 partials
  k_gates_mfma<<<dim3(64, 6), 256, 0, stream>>>(W_ih, xcat, W_hh, prev_h, part);
  k_lstm   <<<dim3(B * H / 256), 256, 0, stream>>>(part, b_ih, b_hh, prev_c,
                                                   lengths, h1, c1);

  // logits = h1 @ W_out^T + b_out, fused log-softmax partials
  k_logits_mfma<<<dim3(V / 64), 256, 0, stream>>>(W_out, h1, logits, b_out, pm, pl);

  // log-softmax over V, in place
  k_lsm_comb<<<dim3(B), 256, 0, stream>>>(pm, pl, lc);
  k_lsm_fin <<<dim3(B * V / 4 / 256), 256, 0, stream>>>(logits, lc);
}